// Round 1
// baseline (794.397 us; speedup 1.0000x reference)
//
#include <hip/hip_runtime.h>
#include <hip/hip_bf16.h>

// Problem: y[n][o] = sum_r sum_m A[r][n][m] * (sum_f X[m][f] * W[r][o][f])
// R=8, N=4096, F_IN=F_OUT=128, all fp32 in / fp32 out.
//
// Strategy: Zt[r][o][m] = (X @ W_r^T)^T in bf16 (kernel 1, 8 MB in d_ws),
// then y = sum_r A_r @ Z_r as one memory-bound bf16-MFMA pass over the
// 512 MiB adjacency (kernel 2), direct-global fragment loads (no LDS, no
// barriers -> no vmcnt(0) barrier drain), r/k-split reduced with hardware
// fp32 atomics onto a zeroed d_out.

#define NN 4096
#define FF 128
#define RR 8
#define KSPLIT 2

typedef __attribute__((ext_vector_type(4))) float  f32x4;
typedef __attribute__((ext_vector_type(8))) __bf16 bf16x8;
typedef __attribute__((ext_vector_type(4))) short  s16x4;

union Frag { unsigned u[4]; bf16x8 v; };

// round-to-nearest-even fp32 -> bf16, two at a time packed into one dword
__device__ __forceinline__ unsigned pk2bf(float a, float b) {
  unsigned ua = __builtin_bit_cast(unsigned, a);
  unsigned ub = __builtin_bit_cast(unsigned, b);
  ua = (ua + (((ua >> 16) & 1u) + 0x7fffu)) >> 16;
  ub = (ub + (((ub >> 16) & 1u) + 0x7fffu)) >> 16;
  return ua | (ub << 16);
}

__device__ __forceinline__ unsigned short f2bf(float a) {
  unsigned ua = __builtin_bit_cast(unsigned, a);
  return (unsigned short)((ua + (((ua >> 16) & 1u) + 0x7fffu)) >> 16);
}

__device__ __forceinline__ void cvt_frag(Frag& f, const f32x4& x0, const f32x4& x1) {
  f.u[0] = pk2bf(x0.x, x0.y);
  f.u[1] = pk2bf(x0.z, x0.w);
  f.u[2] = pk2bf(x1.x, x1.y);
  f.u[3] = pk2bf(x1.z, x1.w);
}

// Kernel 1: Zt[r][o][m] = sum_f X[m][f] * W[r][o][f], bf16 output.
// D[m][o] = X @ W_r^T is a gemm_bt: A-frag from X[m][f] (f contiguous),
// B-frag from W[r][o][f] (f contiguous). Grid (32 mtiles, 8 r), 256 thr.
// Wave w owns rows m0..m0+31 (2 m-tiles) x all 128 o (8 n-tiles).
__global__ __launch_bounds__(256, 2)
void zt_kernel(const float* __restrict__ X, const float* __restrict__ W,
               unsigned short* __restrict__ Zt) {
  const int lane = threadIdx.x & 63;
  const int wave = threadIdx.x >> 6;
  const int quad = lane >> 4;
  const int l16  = lane & 15;
  const int m0   = blockIdx.x * 128 + wave * 32;
  const int r    = blockIdx.y;
  const float* Wr = W + (size_t)r * FF * FF;

  f32x4 acc[2][8] = {};

  #pragma unroll
  for (int k = 0; k < FF; k += 32) {
    Frag a[2], b[8];
    #pragma unroll
    for (int mt = 0; mt < 2; ++mt) {
      const float* p = X + (size_t)(m0 + mt * 16 + l16) * FF + k + quad * 8;
      f32x4 x0 = *(const f32x4*)p;
      f32x4 x1 = *(const f32x4*)(p + 4);
      cvt_frag(a[mt], x0, x1);
    }
    #pragma unroll
    for (int nt = 0; nt < 8; ++nt) {
      const float* p = Wr + (size_t)(nt * 16 + l16) * FF + k + quad * 8;
      f32x4 x0 = *(const f32x4*)p;
      f32x4 x1 = *(const f32x4*)(p + 4);
      cvt_frag(b[nt], x0, x1);
    }
    #pragma unroll
    for (int mt = 0; mt < 2; ++mt)
      #pragma unroll
      for (int nt = 0; nt < 8; ++nt)
        acc[mt][nt] = __builtin_amdgcn_mfma_f32_16x16x32_bf16(
            a[mt].v, b[nt].v, acc[mt][nt], 0, 0, 0);
  }

  // C/D layout: col = lane&15 (o), row = quad*4 + reg (m, consecutive over reg)
  unsigned short* Zr = Zt + (size_t)r * FF * NN;
  #pragma unroll
  for (int mt = 0; mt < 2; ++mt)
    #pragma unroll
    for (int nt = 0; nt < 8; ++nt) {
      const int o = nt * 16 + l16;
      const int m = m0 + mt * 16 + quad * 4;
      s16x4 v;
      v.x = (short)f2bf(acc[mt][nt].x);
      v.y = (short)f2bf(acc[mt][nt].y);
      v.z = (short)f2bf(acc[mt][nt].z);
      v.w = (short)f2bf(acc[mt][nt].w);
      *(s16x4*)(Zr + (size_t)o * NN + m) = v;
    }
}

// Kernel 2: out[n][o] += A_r[n][m-chunk] @ Zt_r[o][m-chunk]^T (bf16 MFMA).
// Grid (32 mtiles, 8 r, KSPLIT). 256 thr = 4 waves, wave owns 32 rows x 128 o.
// No LDS / no barriers: A-frags direct from global fp32 (converted inline),
// B-frags direct from global bf16 (L2-resident Zt). Atomic fp32 reduction.
__global__ __launch_bounds__(256, 2)
void rgcn_main(const float* __restrict__ A, const unsigned short* __restrict__ Zt,
               float* __restrict__ out) {
  const int lane = threadIdx.x & 63;
  const int wave = threadIdx.x >> 6;
  const int quad = lane >> 4;
  const int l16  = lane & 15;
  const int m0   = blockIdx.x * 128 + wave * 32;
  const int r    = blockIdx.y;
  const int k0   = blockIdx.z * (NN / KSPLIT);

  const float* Ar = A + (size_t)r * NN * NN;
  const unsigned short* Zr = Zt + (size_t)r * FF * NN;

  const float* pa0 = Ar + (size_t)(m0 + l16) * NN + quad * 8 + k0;
  const float* pa1 = Ar + (size_t)(m0 + 16 + l16) * NN + quad * 8 + k0;
  const unsigned short* pb[8];
  #pragma unroll
  for (int nt = 0; nt < 8; ++nt)
    pb[nt] = Zr + (size_t)(nt * 16 + l16) * NN + quad * 8 + k0;

  f32x4 acc[2][8] = {};

  #pragma unroll 2
  for (int k = 0; k < NN / KSPLIT; k += 32) {
    Frag a[2];
    {
      f32x4 x0 = *(const f32x4*)(pa0 + k);
      f32x4 x1 = *(const f32x4*)(pa0 + k + 4);
      cvt_frag(a[0], x0, x1);
      f32x4 y0 = *(const f32x4*)(pa1 + k);
      f32x4 y1 = *(const f32x4*)(pa1 + k + 4);
      cvt_frag(a[1], y0, y1);
    }
    bf16x8 b[8];
    #pragma unroll
    for (int nt = 0; nt < 8; ++nt)
      b[nt] = *(const bf16x8*)(pb[nt] + k);

    #pragma unroll
    for (int mt = 0; mt < 2; ++mt)
      #pragma unroll
      for (int nt = 0; nt < 8; ++nt)
        acc[mt][nt] = __builtin_amdgcn_mfma_f32_16x16x32_bf16(
            a[mt].v, b[nt], acc[mt][nt], 0, 0, 0);
  }

  // Epilogue: hardware fp32 atomics (16 partials per output element total).
  #pragma unroll
  for (int mt = 0; mt < 2; ++mt)
    #pragma unroll
    for (int nt = 0; nt < 8; ++nt) {
      const int col = nt * 16 + l16;
      const int row = m0 + mt * 16 + quad * 4;
      unsafeAtomicAdd(&out[(size_t)(row + 0) * FF + col], acc[mt][nt].x);
      unsafeAtomicAdd(&out[(size_t)(row + 1) * FF + col], acc[mt][nt].y);
      unsafeAtomicAdd(&out[(size_t)(row + 2) * FF + col], acc[mt][nt].z);
      unsafeAtomicAdd(&out[(size_t)(row + 3) * FF + col], acc[mt][nt].w);
    }
}

extern "C" void kernel_launch(void* const* d_in, const int* in_sizes, int n_in,
                              void* d_out, int out_size, void* d_ws, size_t ws_size,
                              hipStream_t stream) {
  const float* A = (const float*)d_in[0];  // [8][4096][4096]
  const float* X = (const float*)d_in[1];  // [4096][128]
  const float* W = (const float*)d_in[2];  // [8][128][128]
  float* out = (float*)d_out;              // [4096][128]
  unsigned short* Zt = (unsigned short*)d_ws;  // bf16 [8][128][4096] = 8 MB

  hipMemsetAsync(d_out, 0, (size_t)out_size * sizeof(float), stream);
  zt_kernel<<<dim3(NN / 128, RR), 256, 0, stream>>>(X, W, Zt);
  rgcn_main<<<dim3(NN / 128, RR, KSPLIT), 256, 0, stream>>>(A, Zt, out);
}